// Round 1
// baseline (337.051 us; speedup 1.0000x reference)
//
#include <hip/hip_runtime.h>
#include <hip/hip_bf16.h>

// Problem: B=2048, P=50, C=512, H=7, W=8  ->  M=2048, N=50 (pad 64), K=28672
//   out[b,p] = relu( sum_k x[b,k]^2 + sum_k p[p,k]^2 - 2 * sum_k x[b,k]*p[p,k] )
//
// Round-6 (this round), on top of Round-5's swizzled-B (pb2):
//  (a) A staging made instruction-contiguous: each global_load_dwordx4 now
//      covers one contiguous 64B line per row (lane sq owns floats
//      j*16+sq*4..+3 of the 64-float step) instead of 16B-at-64B-stride.
//      4x fewer TA/L1 line-lookups on the A stream (1024 -> 256 per
//      block-iter) -- same fix class that won on the B side in Round-5.
//  (b) Main-loop __syncthreads() replaced by raw s_barrier + lgkmcnt(0)-only
//      wait. Staging is register-based, so vmcnt drain is NOT needed for
//      correctness; A/B prefetch loads now stay in flight across barriers
//      (T4: counted vmcnt, never 0 in the main loop).

typedef __bf16 bf16_t;
typedef bf16_t bf16x8 __attribute__((ext_vector_type(8)));
typedef bf16_t bf16x4 __attribute__((ext_vector_type(4)));
typedef float  floatx4 __attribute__((ext_vector_type(4)));

#define KDIM 28672
#define BDIM 2048
#define KSPLIT 32
#define KCHUNK (KDIM / KSPLIT)   // 896
#define STEPS (KCHUNK / 64)      // 14 k-steps of 64 per chunk
#define ASTRIDE 72               // LDS row stride in bf16 (64 + 8 pad)
#define PREPSPLIT 8
#define PREPCHUNK (KDIM / PREPSPLIT)  // 3584 floats = 448 octets
// pb2 layout (bf16 units): chunk(ks,step) = (ks*STEPS+step)*4096
//   + half*2048 + ntile*512 + lane*8 + j
//   where lane = q*16 + (p&15), ntile = p>>4, k = ks*896+step*64+half*32+q*8+j

// ---------------- kernel 1: prototype -> swizzled bf16 pb2, p2 partials -----
// grid (64, 8): blockIdx.x = p, blockIdx.y = k-chunk (1/8 of K)
__global__ __launch_bounds__(256) void proto_prep(const float* __restrict__ proto,
                                                  bf16_t* __restrict__ pb2,
                                                  float* __restrict__ p2p) {
    const int p = blockIdx.x;   // 0..63
    const int kc = blockIdx.y;  // 0..7
    const int t = threadIdx.x;  // 0..255
    const int nt = p >> 4;
    const int lr = p & 15;
    float acc = 0.f;

    for (int i = t; i < PREPCHUNK / 8; i += 256) {   // one 8-float octet per iter
        const int kg = kc * PREPCHUNK + i * 8;       // global k of octet start
        bf16x8 o;
        if (p < 50) {
            const float* src = proto + (long)p * KDIM + kg;
            floatx4 v0 = *(const floatx4*)(src);
            floatx4 v1 = *(const floatx4*)(src + 4);
            acc += v0[0]*v0[0] + v0[1]*v0[1] + v0[2]*v0[2] + v0[3]*v0[3]
                 + v1[0]*v1[0] + v1[1]*v1[1] + v1[2]*v1[2] + v1[3]*v1[3];
            o[0]=(bf16_t)v0[0]; o[1]=(bf16_t)v0[1]; o[2]=(bf16_t)v0[2]; o[3]=(bf16_t)v0[3];
            o[4]=(bf16_t)v1[0]; o[5]=(bf16_t)v1[1]; o[6]=(bf16_t)v1[2]; o[7]=(bf16_t)v1[3];
        } else {
            o[0]=(bf16_t)0.f; o[1]=(bf16_t)0.f; o[2]=(bf16_t)0.f; o[3]=(bf16_t)0.f;
            o[4]=(bf16_t)0.f; o[5]=(bf16_t)0.f; o[6]=(bf16_t)0.f; o[7]=(bf16_t)0.f;
        }
        const int ks   = kg / KCHUNK;
        const int kr   = kg % KCHUNK;
        const int step = kr >> 6;
        const int ko   = kr & 63;
        const int h    = ko >> 5;
        const int q    = (ko & 31) >> 3;
        const long addr = (long)(ks * STEPS + step) * 4096 + h * 2048
                        + nt * 512 + (q * 16 + lr) * 8;
        *(bf16x8*)(pb2 + addr) = o;
    }

    __shared__ float sred[256];
    sred[t] = acc;
    __syncthreads();
    for (int s = 128; s > 0; s >>= 1) {
        if (t < s) sred[t] += sred[t + s];
        __syncthreads();
    }
    if (t == 0) p2p[kc * 64 + p] = (p < 50) ? sred[0] : 0.f;
}

// ---------------- kernel 2: main fused GEMM + x2 ----------------
// grid (32, 32): blockIdx.x = M-tile (64 rows), blockIdx.y = K-split
__global__ __launch_bounds__(256, 4) void proto_main(const float* __restrict__ x,
                                                     const bf16_t* __restrict__ pb2,
                                                     float* __restrict__ xpp,
                                                     float* __restrict__ x2p) {
    __shared__ bf16_t As[2][64 * ASTRIDE];   // 2 x 9216 B

    const int t = threadIdx.x;
    const int lane = t & 63;
    const int wave = t >> 6;
    const int lr = lane & 15;
    const int q  = lane >> 4;
    const int mbase = blockIdx.x * 64;
    const int ks = blockIdx.y;
    const int kbase = ks * KCHUNK;

    // ---- staging role: 4 threads per row; instr j covers floats
    //      [j*16, j*16+16) of the 64-float step (contiguous 64B across the
    //      4 lanes of a row); lane sq owns floats j*16 + sq*4 .. +3 ----
    const int srow = t >> 2;
    const int sq   = t & 3;
    const float* xrow = x + (long)(mbase + srow) * KDIM + kbase + sq * 4;
    bf16_t* const awr0 = &As[0][srow * ASTRIDE + sq * 4];
    bf16_t* const awr1 = &As[1][srow * ASTRIDE + sq * 4];

    // ---- compute role: 2x2 wave split over 64x64 tile ----
    const int m0 = (wave >> 1) * 32;
    const int n0 = (wave & 1) * 32;
    const int t0 = (wave & 1) * 2;               // first ntile of this wave
    // coalesced fragment stream: chunk base for this (ks), lane offset baked in
    const bf16_t* bbase = pb2 + (long)ks * STEPS * 4096 + lane * 8;
    const int ard0 = (m0 + lr) * ASTRIDE + q * 8;
    const int ard1 = (m0 + 16 + lr) * ASTRIDE + q * 8;

    floatx4 acc00 = {0.f,0.f,0.f,0.f};
    floatx4 acc01 = {0.f,0.f,0.f,0.f};
    floatx4 acc10 = {0.f,0.f,0.f,0.f};
    floatx4 acc11 = {0.f,0.f,0.f,0.f};
    float x2acc = 0.f;

    // ---- prologue ----
    floatx4 c0 = *(const floatx4*)(xrow);
    floatx4 c1 = *(const floatx4*)(xrow + 16);
    floatx4 c2 = *(const floatx4*)(xrow + 32);
    floatx4 c3 = *(const floatx4*)(xrow + 48);
    // step 0 B fragments (coalesced 1KB segments)
    bf16x8 bc00 = *(const bf16x8*)(bbase + t0 * 512);             // (t0, half0)
    bf16x8 bc01 = *(const bf16x8*)(bbase + 2048 + t0 * 512);      // (t0, half1)
    bf16x8 bc10 = *(const bf16x8*)(bbase + (t0 + 1) * 512);       // (t1, half0)
    bf16x8 bc11 = *(const bf16x8*)(bbase + 2048 + (t0 + 1) * 512);// (t1, half1)
    {
        x2acc += c0[0]*c0[0] + c0[1]*c0[1] + c0[2]*c0[2] + c0[3]*c0[3]
               + c1[0]*c1[0] + c1[1]*c1[1] + c1[2]*c1[2] + c1[3]*c1[3]
               + c2[0]*c2[0] + c2[1]*c2[1] + c2[2]*c2[2] + c2[3]*c2[3]
               + c3[0]*c3[0] + c3[1]*c3[1] + c3[2]*c3[2] + c3[3]*c3[3];
        bf16x4 w0, w1, w2, w3;
        w0[0]=(bf16_t)c0[0]; w0[1]=(bf16_t)c0[1]; w0[2]=(bf16_t)c0[2]; w0[3]=(bf16_t)c0[3];
        w1[0]=(bf16_t)c1[0]; w1[1]=(bf16_t)c1[1]; w1[2]=(bf16_t)c1[2]; w1[3]=(bf16_t)c1[3];
        w2[0]=(bf16_t)c2[0]; w2[1]=(bf16_t)c2[1]; w2[2]=(bf16_t)c2[2]; w2[3]=(bf16_t)c2[3];
        w3[0]=(bf16_t)c3[0]; w3[1]=(bf16_t)c3[1]; w3[2]=(bf16_t)c3[2]; w3[3]=(bf16_t)c3[3];
        *(bf16x4*)(awr0)      = w0;
        *(bf16x4*)(awr0 + 16) = w1;
        *(bf16x4*)(awr0 + 32) = w2;
        *(bf16x4*)(awr0 + 48) = w3;
    }
    // step 1 A -> regs (issued before the barrier; stays in flight across it)
    c0 = *(const floatx4*)(xrow + 64);
    c1 = *(const floatx4*)(xrow + 80);
    c2 = *(const floatx4*)(xrow + 96);
    c3 = *(const floatx4*)(xrow + 112);
    asm volatile("s_waitcnt lgkmcnt(0)" ::: "memory");
    __builtin_amdgcn_s_barrier();

    // ---- main loop: MFMA step it (LDS[it&1] + B regs), convert step it+1,
    //      prefetch A step it+2 / B step it+1. ONE raw barrier per iter,
    //      lgkm-only drain (vmem loads stay in flight across barriers). ----
    #pragma unroll 2
    for (int it = 0; it < STEPS; ++it) {
        const int buf = it & 1;

        // B prefetch: step it+1 (coalesced, L2/L1-resident)
        const int n1 = (it + 1 < STEPS ? it + 1 : STEPS - 1);
        const bf16_t* bp = bbase + n1 * 4096;
        bf16x8 bn00 = *(const bf16x8*)(bp + t0 * 512);
        bf16x8 bn01 = *(const bf16x8*)(bp + 2048 + t0 * 512);
        bf16x8 bn10 = *(const bf16x8*)(bp + (t0 + 1) * 512);
        bf16x8 bn11 = *(const bf16x8*)(bp + 2048 + (t0 + 1) * 512);

        // A prefetch: step it+2 (HBM; 2 iters of slack)
        const int nk2 = (it + 2 < STEPS ? it + 2 : STEPS - 1) * 64;
        floatx4 n0v = *(const floatx4*)(xrow + nk2);
        floatx4 n1v = *(const floatx4*)(xrow + nk2 + 16);
        floatx4 n2v = *(const floatx4*)(xrow + nk2 + 32);
        floatx4 n3v = *(const floatx4*)(xrow + nk2 + 48);

        // convert step it+1 (loaded one full iteration ago) -> LDS[buf^1]
        if (it + 1 < STEPS) {
            x2acc += c0[0]*c0[0] + c0[1]*c0[1] + c0[2]*c0[2] + c0[3]*c0[3]
                   + c1[0]*c1[0] + c1[1]*c1[1] + c1[2]*c1[2] + c1[3]*c1[3]
                   + c2[0]*c2[0] + c2[1]*c2[1] + c2[2]*c2[2] + c2[3]*c2[3]
                   + c3[0]*c3[0] + c3[1]*c3[1] + c3[2]*c3[2] + c3[3]*c3[3];
            bf16_t* aw = buf ? awr0 : awr1;   // write LDS[buf^1]
            bf16x4 w0, w1, w2, w3;
            w0[0]=(bf16_t)c0[0]; w0[1]=(bf16_t)c0[1]; w0[2]=(bf16_t)c0[2]; w0[3]=(bf16_t)c0[3];
            w1[0]=(bf16_t)c1[0]; w1[1]=(bf16_t)c1[1]; w1[2]=(bf16_t)c1[2]; w1[3]=(bf16_t)c1[3];
            w2[0]=(bf16_t)c2[0]; w2[1]=(bf16_t)c2[1]; w2[2]=(bf16_t)c2[2]; w2[3]=(bf16_t)c2[3];
            w3[0]=(bf16_t)c3[0]; w3[1]=(bf16_t)c3[1]; w3[2]=(bf16_t)c3[2]; w3[3]=(bf16_t)c3[3];
            *(bf16x4*)(aw)      = w0;
            *(bf16x4*)(aw + 16) = w1;
            *(bf16x4*)(aw + 32) = w2;
            *(bf16x4*)(aw + 48) = w3;
        }

        // MFMA current step: A from LDS[buf], B from regs (loaded last iter)
        {
            const bf16_t* ab = buf ? &As[1][0] : &As[0][0];
            bf16x8 a00 = *(const bf16x8*)(ab + ard0);
            bf16x8 a01 = *(const bf16x8*)(ab + ard0 + 32);
            bf16x8 a10 = *(const bf16x8*)(ab + ard1);
            bf16x8 a11 = *(const bf16x8*)(ab + ard1 + 32);
            acc00 = __builtin_amdgcn_mfma_f32_16x16x32_bf16(a00, bc00, acc00, 0, 0, 0);
            acc10 = __builtin_amdgcn_mfma_f32_16x16x32_bf16(a10, bc00, acc10, 0, 0, 0);
            acc01 = __builtin_amdgcn_mfma_f32_16x16x32_bf16(a00, bc10, acc01, 0, 0, 0);
            acc11 = __builtin_amdgcn_mfma_f32_16x16x32_bf16(a10, bc10, acc11, 0, 0, 0);
            acc00 = __builtin_amdgcn_mfma_f32_16x16x32_bf16(a01, bc01, acc00, 0, 0, 0);
            acc10 = __builtin_amdgcn_mfma_f32_16x16x32_bf16(a11, bc01, acc10, 0, 0, 0);
            acc01 = __builtin_amdgcn_mfma_f32_16x16x32_bf16(a01, bc11, acc01, 0, 0, 0);
            acc11 = __builtin_amdgcn_mfma_f32_16x16x32_bf16(a11, bc11, acc11, 0, 0, 0);
        }

        // raw barrier: drain LDS ops only (my ds_writes visible + my ds_reads
        // done before anyone overwrites LDS[buf] next iter); global loads
        // (A it+2, B it+1) stay outstanding across the barrier.
        asm volatile("s_waitcnt lgkmcnt(0)" ::: "memory");
        __builtin_amdgcn_s_barrier();
        c0 = n0v; c1 = n1v; c2 = n2v; c3 = n3v;
        bc00 = bn00; bc01 = bn01; bc10 = bn10; bc11 = bn11;
    }

    // ---- xp partials: C/D layout col(n)=lane&15, row(m)=q*4+r ----
    const long base = ((long)ks * BDIM + mbase) * 64;
    #pragma unroll
    for (int r = 0; r < 4; ++r) {
        const int mr = m0 + q * 4 + r;
        xpp[base + (long)mr * 64 + n0 + lr]             = acc00[r];
        xpp[base + (long)mr * 64 + n0 + 16 + lr]        = acc01[r];
        xpp[base + (long)(mr + 16) * 64 + n0 + lr]      = acc10[r];
        xpp[base + (long)(mr + 16) * 64 + n0 + 16 + lr] = acc11[r];
    }

    // ---- x2 partials: 4 staging threads per row -> LDS reduce ----
    float* red = (float*)&As[0][0];
    red[t] = x2acc;          // safe: final loop barrier (lgkm-drained) executed
    __syncthreads();
    if (t < 64) {
        float s = red[4 * t] + red[4 * t + 1] + red[4 * t + 2] + red[4 * t + 3];
        x2p[ks * BDIM + mbase + t] = s;
    }
}

// ---------------- kernel 3: reduce split-K + epilogue ----------------
__global__ __launch_bounds__(256) void proto_finalize(const float* __restrict__ xpp,
                                                      const float* __restrict__ x2p,
                                                      const float* __restrict__ p2p,
                                                      float* __restrict__ out) {
    int idx = blockIdx.x * 256 + threadIdx.x;  // 0 .. 2048*64-1
    int b = idx >> 6;
    int n = idx & 63;
    if (n >= 50) return;
    float xp = 0.f, x2 = 0.f, p2 = 0.f;
    #pragma unroll
    for (int ksi = 0; ksi < KSPLIT; ++ksi) {
        xp += xpp[((long)ksi * BDIM + b) * 64 + n];
        x2 += x2p[ksi * BDIM + b];
    }
    #pragma unroll
    for (int kc = 0; kc < PREPSPLIT; ++kc)
        p2 += p2p[kc * 64 + n];
    float d = x2 + p2 - 2.f * xp;
    out[b * 50 + n] = d > 0.f ? d : 0.f;
}

// ---------------- launch ----------------
extern "C" void kernel_launch(void* const* d_in, const int* in_sizes, int n_in,
                              void* d_out, int out_size, void* d_ws, size_t ws_size,
                              hipStream_t stream) {
    const float* x = (const float*)d_in[0];
    const float* proto = (const float*)d_in[1];
    float* out = (float*)d_out;

    char* ws = (char*)d_ws;
    // ws layout (bytes):
    //   [0)           pb2 (swizzled): 64*28672*2  = 3,670,016
    //   [3,670,016)   p2p:        8*64*4          = 2,048
    //   [3,672,064)   x2p:        32*2048*4       = 262,144
    //   [3,934,208)   xpp:        32*2048*64*4    = 16,777,216   (total ~20.7 MB)
    bf16_t* pb2 = (bf16_t*)(ws);
    float*  p2p = (float*)(ws + 3670016);
    float*  x2p = (float*)(ws + 3672064);
    float*  xpp = (float*)(ws + 3934208);

    proto_prep<<<dim3(64, PREPSPLIT), 256, 0, stream>>>(proto, pb2, p2p);
    proto_main<<<dim3(32, KSPLIT), 256, 0, stream>>>(x, pb2, xpp, x2p);
    proto_finalize<<<(BDIM * 64) / 256, 256, 0, stream>>>(xpp, x2p, p2p, out);
}